// Round 19
// baseline (261.226 us; speedup 1.0000x reference)
//
#include <hip/hip_runtime.h>
#include <hip/hip_bf16.h>

typedef __attribute__((ext_vector_type(4))) short short4v;
typedef __attribute__((ext_vector_type(8))) short short8v;
typedef __attribute__((ext_vector_type(4))) float float4v;
typedef __attribute__((ext_vector_type(2))) unsigned int uint2v;
typedef __attribute__((ext_vector_type(4))) unsigned int uint4v;

#define NTOK 2048      // n = T*S
#define MROWS 4096     // B*n
#define DMODEL 512
#define NINNER 1024
#define DH 64
#define HH 16
#define LOG2E 1.4426950408889634f

__device__ __forceinline__ unsigned short b2s(float f) {
    __hip_bfloat16 h = __float2bfloat16(f);
    return __builtin_bit_cast(unsigned short, h);
}
__device__ __forceinline__ float bf2f(unsigned short h) {
    unsigned int u = ((unsigned int)h) << 16;
    return __builtin_bit_cast(float, u);
}

__device__ __forceinline__ float4v mfma32(short8v a, short8v b, float4v c) {
    return __builtin_amdgcn_mfma_f32_16x16x32_bf16(a, b, c, 0, 0, 0);
}

__device__ __forceinline__ void gld16(const void* g, void* l) {
    __builtin_amdgcn_global_load_lds((const __attribute__((address_space(1))) void*)g,
                                     (__attribute__((address_space(3))) void*)l, 16, 0, 0);
}

// ---- fused prologue (+ attn block schedule) ----
__global__ void k_pre(const float* __restrict__ x, const float* __restrict__ y,
                      const float* __restrict__ pe,
                      unsigned short* __restrict__ xpb, unsigned short* __restrict__ ypb,
                      const float* __restrict__ Wq, const float* __restrict__ Wk,
                      const float* __restrict__ Wv, const float* __restrict__ Wo,
                      const float* __restrict__ gwv, const float* __restrict__ gbv,
                      const float* __restrict__ bo, const int* __restrict__ tmask,
                      unsigned short* __restrict__ wall, unsigned short* __restrict__ wot,
                      float* __restrict__ ctab, float* __restrict__ stab,
                      unsigned short* __restrict__ gvp, float* __restrict__ bgp,
                      int* __restrict__ schd) {
    __shared__ float tl[64][65];
    __shared__ int scnt[64];
    const int blk = blockIdx.x;
    const int tid = threadIdx.x;
    if (blk < 2048) {  // x,y + pos_emb
        int e0 = (blk * 256 + tid) * 4;
        int row = e0 >> 9, col = e0 & 511;
        int t = (row & (NTOK - 1)) >> 7;
        const float4v xv = *(const float4v*)(x + e0);
        const float4v yv = *(const float4v*)(y + e0);
        const float4v pv = *(const float4v*)(pe + t * DMODEL + col);
        short4v xo, yo;
#pragma unroll
        for (int i = 0; i < 4; ++i) {
            xo[i] = (short)b2s(xv[i] + pv[i]);
            yo[i] = (short)b2s(yv[i] + pv[i]);
        }
        *(short4v*)(xpb + e0) = xo;
        *(short4v*)(ypb + e0) = yo;
    } else if (blk < 2560) {  // weight transpose tiles
        int t = blk - 2048;
        const float* W;
        unsigned short* dst;
        int K, N, k0, n0;
        if (t < 384) {
            int which = t / 128, tile = t % 128;
            W = (which == 0) ? Wq : (which == 1) ? Wk : Wv;
            dst = wall + (size_t)which * 1024 * 512;
            K = 512; N = 1024;
            k0 = (tile >> 4) * 64; n0 = (tile & 15) * 64;
        } else {
            int tile = t - 384;
            W = Wo; dst = wot;
            K = 1024; N = 512;
            k0 = (tile >> 3) * 64; n0 = (tile & 7) * 64;
        }
        int tx = tid & 63, ty4 = tid >> 6;
#pragma unroll
        for (int p = 0; p < 16; ++p) {
            int ky = p * 4 + ty4;
            tl[ky][tx] = W[(size_t)(k0 + ky) * N + n0 + tx];
        }
        __syncthreads();
#pragma unroll
        for (int p = 0; p < 16; ++p) {
            int ny = p * 4 + ty4;
            dst[(size_t)(n0 + ny) * K + k0 + tx] = b2s(tl[tx][ny]);
        }
    } else if (blk < 2816) {  // rope tables [2048][32]
        int idx = (blk - 2560) * 256 + tid;
        int p = idx >> 5, j = idx & 31;
        float invf = powf(10000.0f, -(float)(2 * j) * (1.0f / 64.0f));
        float f = (float)p * invf;
        ctab[idx] = cosf(f);
        stab[idx] = sinf(f);
    } else if (blk < 2832) {  // gv = Wo @ gate_w
        int base = (blk - 2816) * 64;
        int w = tid >> 6, l = tid & 63, l16 = l & 15, g = l >> 4;
        int row = base + w * 16 + l16;
        const float* wr = Wo + (size_t)row * 512 + g * 128;
        const float* gr = gwv + g * 128;
        float s = 0.f;
#pragma unroll
        for (int t = 0; t < 32; ++t) {
            float4v a = *(const float4v*)(wr + t * 4);
            float4v b = *(const float4v*)(gr + t * 4);
            s += a[0] * b[0] + a[1] * b[1] + a[2] * b[2] + a[3] * b[3];
        }
        s += __shfl_xor(s, 16);
        s += __shfl_xor(s, 32);
        if (g == 0) gvp[row] = b2s(s);
    } else if (blk == 2832) {  // bg
        if (tid < 64) {
            float s = 0.f;
#pragma unroll
            for (int t = 0; t < 8; ++t) s += bo[tid + t * 64] * gwv[tid + t * 64];
#pragma unroll
            for (int off = 32; off > 0; off >>= 1) s += __shfl_xor(s, off);
            if (tid == 0) bgp[0] = s + gbv[0];
        }
    } else {  // blk in [2833, 2841): attn schedule for XCD group kx
        // Pair high-cnt with low-cnt units within the XCD's 64-block set so the
        // two blocks likely co-resident on a CU (blk j and j+32 of the group)
        // carry complementary work. Pure permutation -> correctness-neutral.
        int kx = blk - 2833;
        if (tid < 64) {
            int uu = kx * 64 + tid;
            int tti = uu & 15, bb = uu >> 8;
            int m = 0;
#pragma unroll
            for (int jj = 0; jj < 16; ++jj)
                m += (tmask[(bb * 16 + tti) * 16 + jj] != 0);
            scnt[tid] = m;
        }
        __syncthreads();
        if (tid == 0) {
            int cnt[64], idx[64];
            for (int j = 0; j < 64; ++j) { cnt[j] = scnt[j]; idx[j] = j; }
            for (int a = 1; a < 64; ++a) {  // insertion sort, descending
                int c = cnt[a], id = idx[a], p = a - 1;
                while (p >= 0 && cnt[p] < c) { cnt[p+1] = cnt[p]; idx[p+1] = idx[p]; --p; }
                cnt[p+1] = c; idx[p+1] = id;
            }
            for (int j = 0; j < 32; ++j) {
                schd[8 * j + kx] = kx * 64 + idx[j];
                schd[8 * (j + 32) + kx] = kx * 64 + idx[63 - j];
            }
        }
    }
}

// ---- QKV GEMM: 128x128 tile, BK=32, 4 waves (2x2), 4x4 frags/wave ----
__global__ __launch_bounds__(256) void k_qkv(const unsigned short* __restrict__ A,
                                             const unsigned short* __restrict__ A2,
                                             const unsigned short* __restrict__ Bt,
                                             unsigned short* __restrict__ Cq,
                                             unsigned short* __restrict__ Ck,
                                             unsigned short* __restrict__ Cvv,
                                             const float* __restrict__ ctab,
                                             const float* __restrict__ stab,
                                             float scale) {
    __shared__ unsigned short Ab[2][4096];
    __shared__ unsigned short Bb[2][4096];
    const int tid = threadIdx.x;
    const int w = tid >> 6, l = tid & 63, l16 = l & 15, g = l >> 4;
    const int wm = w >> 1, wn = w & 1;
    const int m0 = blockIdx.y * 128, n0 = blockIdx.x * 128;
    const unsigned short* Ap = (n0 >= 2048) ? A2 : A;
    float4v acc[4][4];
#pragma unroll
    for (int i = 0; i < 4; ++i)
#pragma unroll
        for (int j = 0; j < 4; ++j) acc[i][j] = (float4v){0.f, 0.f, 0.f, 0.f};

    auto stage = [&](int t, int buf) {
        int k0 = t * 32;
#pragma unroll
        for (int it = 0; it < 2; ++it) {
            int f = it * 4 + w;
            gld16(Ap + (size_t)(m0 + f * 16 + l16) * 512 + k0 + g * 8, &Ab[buf][f * 512]);
            gld16(Bt + (size_t)(n0 + f * 16 + l16) * 512 + k0 + g * 8, &Bb[buf][f * 512]);
        }
    };

    stage(0, 0);
    __syncthreads();
    for (int t = 0; t < 16; ++t) {
        const int cur = t & 1;
        if (t + 1 < 16) stage(t + 1, cur ^ 1);
        short8v af[4], bf[4];
#pragma unroll
        for (int mi = 0; mi < 4; ++mi)
            af[mi] = *(const short8v*)&Ab[cur][(wm * 4 + mi) * 512 + l * 8];
#pragma unroll
        for (int nj = 0; nj < 4; ++nj)
            bf[nj] = *(const short8v*)&Bb[cur][(wn * 4 + nj) * 512 + l * 8];
        __builtin_amdgcn_s_setprio(1);
#pragma unroll
        for (int mi = 0; mi < 4; ++mi)
#pragma unroll
            for (int nj = 0; nj < 4; ++nj)
                acc[mi][nj] = mfma32(af[mi], bf[nj], acc[mi][nj]);
        __builtin_amdgcn_s_setprio(0);
        __syncthreads();
    }

    const int hh = (n0 + wn * 64) >> 6;
    const int head = hh & 15;
    if (hh < 32) {
        unsigned short* out = (hh < 16) ? Cq : Ck;
        const float sc = (hh < 16) ? scale : 1.0f;
#pragma unroll
        for (int mi = 0; mi < 4; ++mi)
#pragma unroll
            for (int r = 0; r < 4; ++r) {
                int row = m0 + wm * 64 + mi * 16 + g * 4 + r;
                int b = row >> 11, pos = row & (NTOK - 1);
                const float* cr = ctab + pos * 32;
                const float* sr = stab + pos * 32;
                unsigned short* ob = out + (size_t)((b * HH + head) * NTOK + pos) * DH;
#pragma unroll
                for (int nj = 0; nj < 2; ++nj) {
                    int j = nj * 16 + l16;
                    float c = cr[j], s = sr[j];
                    float v1 = acc[mi][nj][r], v2 = acc[mi][nj + 2][r];
                    ob[j] = b2s((v1 * c - v2 * s) * sc);
                    ob[j + 32] = b2s((v2 * c + v1 * s) * sc);
                }
            }
    } else {
#pragma unroll
        for (int mi = 0; mi < 4; ++mi)
#pragma unroll
            for (int nj = 0; nj < 4; ++nj) {
                int d = nj * 16 + l16;
                int row0 = m0 + wm * 64 + mi * 16 + g * 4;
                int b = row0 >> 11, pos0 = row0 & (NTOK - 1);
                short4v o;
#pragma unroll
                for (int r = 0; r < 4; ++r) o[r] = (short)b2s(acc[mi][nj][r]);
                *(short4v*)(Cvv + (size_t)((b * HH + head) * DH + d) * NTOK + pos0) = o;
            }
    }
}

// ---- O-projection v3: 64x64 tile, grid (8,64); gate-dot fused via broadcast-B MFMA ----
__global__ __launch_bounds__(256) void k_oproj(const unsigned short* __restrict__ A,
                                               const unsigned short* __restrict__ Bt,
                                               const float* __restrict__ bo,
                                               const unsigned short* __restrict__ gv,
                                               const float* __restrict__ bgp,
                                               float* __restrict__ out) {
    __shared__ unsigned short Ab[2][2048];  // 4 frags x 512 shorts (64 rows x 32 k)
    __shared__ unsigned short Bb[2][2048];
    const int tid = threadIdx.x;
    const int w = tid >> 6, l = tid & 63, l16 = l & 15, g = l >> 4;
    const int m0 = blockIdx.y * 64, n0 = blockIdx.x * 64;
    float4v acc[4];
#pragma unroll
    for (int j = 0; j < 4; ++j) acc[j] = (float4v){0.f, 0.f, 0.f, 0.f};
    float4v gacc = (float4v){0.f, 0.f, 0.f, 0.f};

    auto stage = [&](int t, int buf) {
        int k0 = t * 32;
        gld16(A + (size_t)(m0 + w * 16 + l16) * 1024 + k0 + g * 8, &Ab[buf][w * 512]);
        gld16(Bt + (size_t)(n0 + w * 16 + l16) * 1024 + k0 + g * 8, &Bb[buf][w * 512]);
    };

    stage(0, 0);
    __syncthreads();
    for (int t = 0; t < 32; ++t) {
        const int cur = t & 1;
        if (t + 1 < 32) stage(t + 1, cur ^ 1);
        short8v af = *(const short8v*)&Ab[cur][w * 512 + l * 8];
        short8v bf[4];
#pragma unroll
        for (int nj = 0; nj < 4; ++nj)
            bf[nj] = *(const short8v*)&Bb[cur][nj * 512 + l * 8];
        short8v gvf = *(const short8v*)(gv + t * 32 + g * 8);  // broadcast B-frag
        __builtin_amdgcn_s_setprio(1);
#pragma unroll
        for (int nj = 0; nj < 4; ++nj)
            acc[nj] = mfma32(af, bf[nj], acc[nj]);
        gacc = mfma32(af, gvf, gacc);
        __builtin_amdgcn_s_setprio(0);
        __syncthreads();
    }
    const float bg = bgp[0];
    float gl[4];
#pragma unroll
    for (int r = 0; r < 4; ++r) gl[r] = 1.0f / (1.0f + __expf(-(gacc[r] + bg)));
#pragma unroll
    for (int nj = 0; nj < 4; ++nj) {
        int col = n0 + nj * 16 + l16;
        float bv = bo[col];
#pragma unroll
        for (int r = 0; r < 4; ++r) {
            int row = m0 + w * 16 + g * 4 + r;
            out[(size_t)row * 512 + col] = (acc[nj][r] + bv) * gl[r];
        }
    }
}

// ---- masked flash attention v10 + scheduled block->unit map ----
// 8 waves/512 thr, wave owns 16 q-rows, KVBLK=64, grid 512. u = schd[blk]:
// complementary-cost pairing within each XCD group (L2 locality preserved).
// K TRIPLE-buffered (staged distance-2 via gld16); V double-buffered (reg->LDS).
__global__ __launch_bounds__(512) void k_attn(const unsigned short* __restrict__ qh,
                                              const unsigned short* __restrict__ kh,
                                              const unsigned short* __restrict__ vt,
                                              const int* __restrict__ tmask,
                                              const int* __restrict__ schd,
                                              unsigned short* __restrict__ otmp) {
    __shared__ unsigned short Kb[3][4096];  // 8 frags x 512 shorts (64 kv x 64 d)
    __shared__ unsigned short Vb[2][4096];
    __shared__ int tlist[33];
    const int blk = blockIdx.x;
    const int u = schd[blk];
    const int ti = u & 15, h = (u >> 4) & 15, b = u >> 8;
    const int tid = threadIdx.x, w = tid >> 6, l = tid & 63, l16 = l & 15, g = l >> 4;
    if (tid == 0) {
        int c = 0;
        for (int j = 0; j < 16; ++j)
            if (tmask[(b * 16 + ti) * 16 + j]) { tlist[c++] = 2 * j; tlist[c++] = 2 * j + 1; }
        tlist[32] = c;
    }
    __syncthreads();
    const int cnt = tlist[32];
    const unsigned short* qb = qh + (size_t)((b * HH + h) * NTOK) * DH;
    const unsigned short* kb = kh + (size_t)((b * HH + h) * NTOK) * DH;
    const unsigned short* vb = vt + (size_t)((b * HH + h) * DH) * NTOK;
    const int q0 = ti * 128 + w * 16;

    short8v qf[2];
#pragma unroll
    for (int c = 0; c < 2; ++c)
        qf[c] = *(const short8v*)(qb + (size_t)(q0 + l16) * DH + c * 32 + g * 8);

    short8v ones;  // all-ones bf16 A-frag for the MFMA row-sum
#pragma unroll
    for (int j = 0; j < 8; ++j) ones[j] = (short)0x3F80;

    float4v oacc[4];
#pragma unroll
    for (int i = 0; i < 4; ++i) oacc[i] = (float4v){0.f, 0.f, 0.f, 0.f};
    float4v lsum = (float4v){0.f, 0.f, 0.f, 0.f};
    float mx = -1e30f;
    uint4v vrg;
    float4v sA[4], sB[4];

    auto stageK = [&](int st, int buf) {
        const unsigned short* ga =
            kb + (size_t)(st * 64 + (w >> 1) * 16 + l16) * DH + (w & 1) * 32 + g * 8;
        gld16(ga, &Kb[buf][w * 512]);
    };
    auto loadV = [&](int st) {
        const unsigned short* ga =
            vb + (size_t)((w >> 1) * 16 + l16) * NTOK + st * 64 + (w & 1) * 32 + g * 4;
        uint2v lo = *(const uint2v*)ga;
        uint2v hi = *(const uint2v*)(ga + 16);
        vrg = (uint4v){lo[0], lo[1], hi[0], hi[1]};
    };
    auto writeV = [&](int buf) {
        *(uint4v*)&Vb[buf][w * 512 + l * 8] = vrg;
    };
    auto qkcomp = [&](int buf, float4v (&s)[4]) {
#pragma unroll
        for (int jk = 0; jk < 4; ++jk) s[jk] = (float4v){0.f, 0.f, 0.f, 0.f};
        __builtin_amdgcn_s_setprio(1);
#pragma unroll
        for (int jk = 0; jk < 4; ++jk) {
            short8v kf0 = *(const short8v*)&Kb[buf][(jk * 2 + 0) * 512 + l * 8];
            short8v kf1 = *(const short8v*)&Kb[buf][(jk * 2 + 1) * 512 + l * 8];
            s[jk] = mfma32(kf0, qf[0], s[jk]);
            s[jk] = mfma32(kf1, qf[1], s[jk]);
        }
        __builtin_amdgcn_s_setprio(0);
    };

    auto body = [&](int i, float4v (&scur)[4], float4v (&snext)[4]) {
        const bool pre1 = (i + 1 < cnt), pre2 = (i + 2 < cnt);
        if (pre2) stageK(tlist[i + 2], (i + 2) % 3);
        if (pre1) loadV(tlist[i + 1]);
        // ---- max-reduce + defer-max rescale on scur ----
        float tm = -1e30f;
#pragma unroll
        for (int jk = 0; jk < 4; ++jk) {
            float4v s4 = scur[jk];
            tm = fmaxf(tm, fmaxf(fmaxf(s4[0], s4[1]), fmaxf(s4[2], s4[3])));
        }
        tm = fmaxf(tm, __shfl_xor(tm, 16));
        tm = fmaxf(tm, __shfl_xor(tm, 32));
        if (!__all(tm <= mx + 8.0f)) {
            float mnew = fmaxf(mx, tm);
            float alpha = exp2f(mx - mnew);
#pragma unroll
            for (int r = 0; r < 4; ++r) lsum[r] *= alpha;
#pragma unroll
            for (int md = 0; md < 4; ++md)
#pragma unroll
                for (int r = 0; r < 4; ++r) oacc[md][r] *= alpha;
            mx = mnew;
        }
        // ---- QK(i+1) into the other sacc bank (overlaps exps below) ----
        if (pre1) qkcomp((i + 1) % 3, snext);
        // ---- exps + pack (VALU/trans pipe) ----
        short8v pf[2];
#pragma unroll
        for (int cc = 0; cc < 2; ++cc) {
            short8v pv;
#pragma unroll
            for (int r = 0; r < 4; ++r) {
                pv[r] = (short)b2s(exp2f(scur[2 * cc][r] - mx));
                pv[r + 4] = (short)b2s(exp2f(scur[2 * cc + 1][r] - mx));
            }
            pf[cc] = pv;
        }
        // ---- PV(i) + MFMA row-sum from Vb[i&1] ----
        __builtin_amdgcn_s_setprio(1);
#pragma unroll
        for (int cc = 0; cc < 2; ++cc) lsum = mfma32(ones, pf[cc], lsum);
#pragma unroll
        for (int md = 0; md < 4; ++md)
#pragma unroll
            for (int cc = 0; cc < 2; ++cc) {
                short8v vf = *(const short8v*)&Vb[i & 1][(md * 2 + cc) * 512 + l * 8];
                oacc[md] = mfma32(vf, pf[cc], oacc[md]);
            }
        __builtin_amdgcn_s_setprio(0);
        if (pre1) writeV((i + 1) & 1);
        __syncthreads();  // drains K staging; V(i+1) visible; all reads of this iter done
    };

    if (cnt > 0) {
        stageK(tlist[0], 0);
        loadV(tlist[0]);
        if (cnt > 1) stageK(tlist[1], 1);
        writeV(0);
        __syncthreads();   // K(0),K(1) staged + V(0) visible
        qkcomp(0, sA);     // QK(0)
        for (int i = 0; i < cnt; i += 2) {
            body(i, sA, sB);
            if (i + 1 < cnt) body(i + 1, sB, sA);
        }
    }
    float lrow = lsum[0];
    float inv = lrow > 0.f ? 1.0f / lrow : 0.f;
    int q = q0 + l16;
#pragma unroll
    for (int md = 0; md < 4; ++md) {
        short4v o;
#pragma unroll
        for (int r = 0; r < 4; ++r) o[r] = (short)b2s(oacc[md][r] * inv);
        *(short4v*)(otmp + (size_t)(b * NTOK + q) * NINNER + h * DH + md * 16 + g * 4) = o;
    }
}

extern "C" void kernel_launch(void* const* d_in, const int* in_sizes, int n_in,
                              void* d_out, int out_size, void* d_ws, size_t ws_size,
                              hipStream_t stream) {
    (void)in_sizes; (void)n_in; (void)out_size; (void)ws_size;
    const float* x = (const float*)d_in[0];
    const float* y = (const float*)d_in[1];
    const int* tmask = (const int*)d_in[2];
    const float* Wq = (const float*)d_in[3];
    const float* Wk = (const float*)d_in[4];
    const float* Wv = (const float*)d_in[5];
    const float* Wo = (const float*)d_in[6];
    const float* bo = (const float*)d_in[7];
    const float* pe = (const float*)d_in[8];
    const float* gw = (const float*)d_in[9];
    const float* gb = (const float*)d_in[10];

    char* ws = (char*)d_ws;
    const size_t MB = 1u << 20;
    unsigned short* xpb  = (unsigned short*)(ws + 0);         // 4MB
    unsigned short* ypb  = (unsigned short*)(ws + 4 * MB);    // 4MB
    unsigned short* wall = (unsigned short*)(ws + 8 * MB);    // 3MB [3072][512]
    unsigned short* wot  = (unsigned short*)(ws + 11 * MB);   // 1MB [512][1024]
    unsigned short* qh   = (unsigned short*)(ws + 12 * MB);   // 8MB  [B,H,n,64] bf16
    unsigned short* kh   = (unsigned short*)(ws + 20 * MB);   // 8MB
    unsigned short* vt   = (unsigned short*)(ws + 28 * MB);   // 8MB  [B,H,64,n] bf16
    unsigned short* otm  = (unsigned short*)(ws + 36 * MB);   // 8MB  [B*n,1024] bf16
    float* ct = (float*)(ws + 44 * MB);                       // 256KB
    float* st = (float*)(ws + 44 * MB + 256 * 1024);          // 256KB
    unsigned short* gv = (unsigned short*)(ws + 45 * MB);     // 2KB
    float* bg = (float*)(ws + 45 * MB + 4096);                // 4B
    int* schd = (int*)(ws + 45 * MB + 8192);                  // 2KB
    float* outp = (float*)d_out;

    k_pre<<<2841, 256, 0, stream>>>(x, y, pe, xpb, ypb, Wq, Wk, Wv, Wo, gw, gb, bo,
                                    tmask, wall, wot, ct, st, gv, bg, schd);
    // merged QKV: q,k from x (bug-compatible with reference); v from y.
    k_qkv<<<dim3(24, 32), 256, 0, stream>>>(xpb, ypb, wall, qh, kh, vt, ct, st,
                                            0.125f * LOG2E);
    k_attn<<<512, 512, 0, stream>>>(qh, kh, vt, tmask, schd, otm);
    k_oproj<<<dim3(8, 64), 256, 0, stream>>>(otm, wot, bo, gv, bg, outp);
}

// Round 20
// 115.578 us; speedup vs baseline: 2.2602x; 2.2602x over previous
//
#include <hip/hip_runtime.h>
#include <hip/hip_bf16.h>

typedef __attribute__((ext_vector_type(4))) short short4v;
typedef __attribute__((ext_vector_type(8))) short short8v;
typedef __attribute__((ext_vector_type(4))) float float4v;
typedef __attribute__((ext_vector_type(2))) unsigned int uint2v;
typedef __attribute__((ext_vector_type(4))) unsigned int uint4v;

#define NTOK 2048      // n = T*S
#define MROWS 4096     // B*n
#define DMODEL 512
#define NINNER 1024
#define DH 64
#define HH 16
#define LOG2E 1.4426950408889634f

__device__ __forceinline__ unsigned short b2s(float f) {
    __hip_bfloat16 h = __float2bfloat16(f);
    return __builtin_bit_cast(unsigned short, h);
}
__device__ __forceinline__ float bf2f(unsigned short h) {
    unsigned int u = ((unsigned int)h) << 16;
    return __builtin_bit_cast(float, u);
}

__device__ __forceinline__ float4v mfma32(short8v a, short8v b, float4v c) {
    return __builtin_amdgcn_mfma_f32_16x16x32_bf16(a, b, c, 0, 0, 0);
}

__device__ __forceinline__ void gld16(const void* g, void* l) {
    __builtin_amdgcn_global_load_lds((const __attribute__((address_space(1))) void*)g,
                                     (__attribute__((address_space(3))) void*)l, 16, 0, 0);
}

// ---- fused prologue ----
__global__ void k_pre(const float* __restrict__ x, const float* __restrict__ y,
                      const float* __restrict__ pe,
                      unsigned short* __restrict__ xpb, unsigned short* __restrict__ ypb,
                      const float* __restrict__ Wq, const float* __restrict__ Wk,
                      const float* __restrict__ Wv, const float* __restrict__ Wo,
                      const float* __restrict__ gwv, const float* __restrict__ gbv,
                      const float* __restrict__ bo,
                      unsigned short* __restrict__ wall, unsigned short* __restrict__ wot,
                      float* __restrict__ ctab, float* __restrict__ stab,
                      unsigned short* __restrict__ gvp, float* __restrict__ bgp) {
    __shared__ float tl[64][65];
    const int blk = blockIdx.x;
    const int tid = threadIdx.x;
    if (blk < 2048) {  // x,y + pos_emb
        int e0 = (blk * 256 + tid) * 4;
        int row = e0 >> 9, col = e0 & 511;
        int t = (row & (NTOK - 1)) >> 7;
        const float4v xv = *(const float4v*)(x + e0);
        const float4v yv = *(const float4v*)(y + e0);
        const float4v pv = *(const float4v*)(pe + t * DMODEL + col);
        short4v xo, yo;
#pragma unroll
        for (int i = 0; i < 4; ++i) {
            xo[i] = (short)b2s(xv[i] + pv[i]);
            yo[i] = (short)b2s(yv[i] + pv[i]);
        }
        *(short4v*)(xpb + e0) = xo;
        *(short4v*)(ypb + e0) = yo;
    } else if (blk < 2560) {  // weight transpose tiles
        int t = blk - 2048;
        const float* W;
        unsigned short* dst;
        int K, N, k0, n0;
        if (t < 384) {
            int which = t / 128, tile = t % 128;
            W = (which == 0) ? Wq : (which == 1) ? Wk : Wv;
            dst = wall + (size_t)which * 1024 * 512;
            K = 512; N = 1024;
            k0 = (tile >> 4) * 64; n0 = (tile & 15) * 64;
        } else {
            int tile = t - 384;
            W = Wo; dst = wot;
            K = 1024; N = 512;
            k0 = (tile >> 3) * 64; n0 = (tile & 7) * 64;
        }
        int tx = tid & 63, ty4 = tid >> 6;
#pragma unroll
        for (int p = 0; p < 16; ++p) {
            int ky = p * 4 + ty4;
            tl[ky][tx] = W[(size_t)(k0 + ky) * N + n0 + tx];
        }
        __syncthreads();
#pragma unroll
        for (int p = 0; p < 16; ++p) {
            int ny = p * 4 + ty4;
            dst[(size_t)(n0 + ny) * K + k0 + tx] = b2s(tl[tx][ny]);
        }
    } else if (blk < 2816) {  // rope tables [2048][32]
        int idx = (blk - 2560) * 256 + tid;
        int p = idx >> 5, j = idx & 31;
        float invf = powf(10000.0f, -(float)(2 * j) * (1.0f / 64.0f));
        float f = (float)p * invf;
        ctab[idx] = cosf(f);
        stab[idx] = sinf(f);
    } else if (blk < 2832) {  // gv = Wo @ gate_w
        int base = (blk - 2816) * 64;
        int w = tid >> 6, l = tid & 63, l16 = l & 15, g = l >> 4;
        int row = base + w * 16 + l16;
        const float* wr = Wo + (size_t)row * 512 + g * 128;
        const float* gr = gwv + g * 128;
        float s = 0.f;
#pragma unroll
        for (int t = 0; t < 32; ++t) {
            float4v a = *(const float4v*)(wr + t * 4);
            float4v b = *(const float4v*)(gr + t * 4);
            s += a[0] * b[0] + a[1] * b[1] + a[2] * b[2] + a[3] * b[3];
        }
        s += __shfl_xor(s, 16);
        s += __shfl_xor(s, 32);
        if (g == 0) gvp[row] = b2s(s);
    } else {  // bg
        if (tid < 64) {
            float s = 0.f;
#pragma unroll
            for (int t = 0; t < 8; ++t) s += bo[tid + t * 64] * gwv[tid + t * 64];
#pragma unroll
            for (int off = 32; off > 0; off >>= 1) s += __shfl_xor(s, off);
            if (tid == 0) bgp[0] = s + gbv[0];
        }
    }
}

// ---- QKV GEMM: 128x128 tile, BK=32, 4 waves (2x2), 4x4 frags/wave ----
__global__ __launch_bounds__(256) void k_qkv(const unsigned short* __restrict__ A,
                                             const unsigned short* __restrict__ A2,
                                             const unsigned short* __restrict__ Bt,
                                             unsigned short* __restrict__ Cq,
                                             unsigned short* __restrict__ Ck,
                                             unsigned short* __restrict__ Cvv,
                                             const float* __restrict__ ctab,
                                             const float* __restrict__ stab,
                                             float scale) {
    __shared__ unsigned short Ab[2][4096];
    __shared__ unsigned short Bb[2][4096];
    const int tid = threadIdx.x;
    const int w = tid >> 6, l = tid & 63, l16 = l & 15, g = l >> 4;
    const int wm = w >> 1, wn = w & 1;
    const int m0 = blockIdx.y * 128, n0 = blockIdx.x * 128;
    const unsigned short* Ap = (n0 >= 2048) ? A2 : A;
    float4v acc[4][4];
#pragma unroll
    for (int i = 0; i < 4; ++i)
#pragma unroll
        for (int j = 0; j < 4; ++j) acc[i][j] = (float4v){0.f, 0.f, 0.f, 0.f};

    auto stage = [&](int t, int buf) {
        int k0 = t * 32;
#pragma unroll
        for (int it = 0; it < 2; ++it) {
            int f = it * 4 + w;
            gld16(Ap + (size_t)(m0 + f * 16 + l16) * 512 + k0 + g * 8, &Ab[buf][f * 512]);
            gld16(Bt + (size_t)(n0 + f * 16 + l16) * 512 + k0 + g * 8, &Bb[buf][f * 512]);
        }
    };

    stage(0, 0);
    __syncthreads();
    for (int t = 0; t < 16; ++t) {
        const int cur = t & 1;
        if (t + 1 < 16) stage(t + 1, cur ^ 1);
        short8v af[4], bf[4];
#pragma unroll
        for (int mi = 0; mi < 4; ++mi)
            af[mi] = *(const short8v*)&Ab[cur][(wm * 4 + mi) * 512 + l * 8];
#pragma unroll
        for (int nj = 0; nj < 4; ++nj)
            bf[nj] = *(const short8v*)&Bb[cur][(wn * 4 + nj) * 512 + l * 8];
        __builtin_amdgcn_s_setprio(1);
#pragma unroll
        for (int mi = 0; mi < 4; ++mi)
#pragma unroll
            for (int nj = 0; nj < 4; ++nj)
                acc[mi][nj] = mfma32(af[mi], bf[nj], acc[mi][nj]);
        __builtin_amdgcn_s_setprio(0);
        __syncthreads();
    }

    const int hh = (n0 + wn * 64) >> 6;
    const int head = hh & 15;
    if (hh < 32) {
        unsigned short* out = (hh < 16) ? Cq : Ck;
        const float sc = (hh < 16) ? scale : 1.0f;
#pragma unroll
        for (int mi = 0; mi < 4; ++mi)
#pragma unroll
            for (int r = 0; r < 4; ++r) {
                int row = m0 + wm * 64 + mi * 16 + g * 4 + r;
                int b = row >> 11, pos = row & (NTOK - 1);
                const float* cr = ctab + pos * 32;
                const float* sr = stab + pos * 32;
                unsigned short* ob = out + (size_t)((b * HH + head) * NTOK + pos) * DH;
#pragma unroll
                for (int nj = 0; nj < 2; ++nj) {
                    int j = nj * 16 + l16;
                    float c = cr[j], s = sr[j];
                    float v1 = acc[mi][nj][r], v2 = acc[mi][nj + 2][r];
                    ob[j] = b2s((v1 * c - v2 * s) * sc);
                    ob[j + 32] = b2s((v2 * c + v1 * s) * sc);
                }
            }
    } else {
#pragma unroll
        for (int mi = 0; mi < 4; ++mi)
#pragma unroll
            for (int nj = 0; nj < 4; ++nj) {
                int d = nj * 16 + l16;
                int row0 = m0 + wm * 64 + mi * 16 + g * 4;
                int b = row0 >> 11, pos0 = row0 & (NTOK - 1);
                short4v o;
#pragma unroll
                for (int r = 0; r < 4; ++r) o[r] = (short)b2s(acc[mi][nj][r]);
                *(short4v*)(Cvv + (size_t)((b * HH + head) * DH + d) * NTOK + pos0) = o;
            }
    }
}

// ---- O-projection v3: 64x64 tile, grid (8,64); gate-dot fused via broadcast-B MFMA ----
__global__ __launch_bounds__(256) void k_oproj(const unsigned short* __restrict__ A,
                                               const unsigned short* __restrict__ Bt,
                                               const float* __restrict__ bo,
                                               const unsigned short* __restrict__ gv,
                                               const float* __restrict__ bgp,
                                               float* __restrict__ out) {
    __shared__ unsigned short Ab[2][2048];  // 4 frags x 512 shorts (64 rows x 32 k)
    __shared__ unsigned short Bb[2][2048];
    const int tid = threadIdx.x;
    const int w = tid >> 6, l = tid & 63, l16 = l & 15, g = l >> 4;
    const int m0 = blockIdx.y * 64, n0 = blockIdx.x * 64;
    float4v acc[4];
#pragma unroll
    for (int j = 0; j < 4; ++j) acc[j] = (float4v){0.f, 0.f, 0.f, 0.f};
    float4v gacc = (float4v){0.f, 0.f, 0.f, 0.f};

    auto stage = [&](int t, int buf) {
        int k0 = t * 32;
        gld16(A + (size_t)(m0 + w * 16 + l16) * 1024 + k0 + g * 8, &Ab[buf][w * 512]);
        gld16(Bt + (size_t)(n0 + w * 16 + l16) * 1024 + k0 + g * 8, &Bb[buf][w * 512]);
    };

    stage(0, 0);
    __syncthreads();
    for (int t = 0; t < 32; ++t) {
        const int cur = t & 1;
        if (t + 1 < 32) stage(t + 1, cur ^ 1);
        short8v af = *(const short8v*)&Ab[cur][w * 512 + l * 8];
        short8v bf[4];
#pragma unroll
        for (int nj = 0; nj < 4; ++nj)
            bf[nj] = *(const short8v*)&Bb[cur][nj * 512 + l * 8];
        short8v gvf = *(const short8v*)(gv + t * 32 + g * 8);  // broadcast B-frag
        __builtin_amdgcn_s_setprio(1);
#pragma unroll
        for (int nj = 0; nj < 4; ++nj)
            acc[nj] = mfma32(af, bf[nj], acc[nj]);
        gacc = mfma32(af, gvf, gacc);
        __builtin_amdgcn_s_setprio(0);
        __syncthreads();
    }
    const float bg = bgp[0];
    float gl[4];
#pragma unroll
    for (int r = 0; r < 4; ++r) gl[r] = 1.0f / (1.0f + __expf(-(gacc[r] + bg)));
#pragma unroll
    for (int nj = 0; nj < 4; ++nj) {
        int col = n0 + nj * 16 + l16;
        float bv = bo[col];
#pragma unroll
        for (int r = 0; r < 4; ++r) {
            int row = m0 + w * 16 + g * 4 + r;
            out[(size_t)row * 512 + col] = (acc[nj][r] + bv) * gl[r];
        }
    }
}

// ---- masked flash attention v10 (R11/R15-proven, 60.0us): QK(i+1) overlaps softmax(i) ----
// 8 waves/512 thr, wave owns 16 q-rows, KVBLK=64, grid 512 (XCD swizzle).
// K TRIPLE-buffered (staged distance-2 via gld16); V double-buffered (reg->LDS).
__global__ __launch_bounds__(512) void k_attn(const unsigned short* __restrict__ qh,
                                              const unsigned short* __restrict__ kh,
                                              const unsigned short* __restrict__ vt,
                                              const int* __restrict__ tmask,
                                              unsigned short* __restrict__ otmp) {
    __shared__ unsigned short Kb[3][4096];  // 8 frags x 512 shorts (64 kv x 64 d)
    __shared__ unsigned short Vb[2][4096];
    __shared__ int tlist[33];
    const int blk = blockIdx.x;
    const int u = (blk & 7) * 64 + (blk >> 3);  // bijective XCD chunking (512 % 8 == 0)
    const int ti = u & 15, h = (u >> 4) & 15, b = u >> 8;
    const int tid = threadIdx.x, w = tid >> 6, l = tid & 63, l16 = l & 15, g = l >> 4;
    if (tid == 0) {
        int c = 0;
        for (int j = 0; j < 16; ++j)
            if (tmask[(b * 16 + ti) * 16 + j]) { tlist[c++] = 2 * j; tlist[c++] = 2 * j + 1; }
        tlist[32] = c;
    }
    __syncthreads();
    const int cnt = tlist[32];
    const unsigned short* qb = qh + (size_t)((b * HH + h) * NTOK) * DH;
    const unsigned short* kb = kh + (size_t)((b * HH + h) * NTOK) * DH;
    const unsigned short* vb = vt + (size_t)((b * HH + h) * DH) * NTOK;
    const int q0 = ti * 128 + w * 16;

    short8v qf[2];
#pragma unroll
    for (int c = 0; c < 2; ++c)
        qf[c] = *(const short8v*)(qb + (size_t)(q0 + l16) * DH + c * 32 + g * 8);

    short8v ones;  // all-ones bf16 A-frag for the MFMA row-sum
#pragma unroll
    for (int j = 0; j < 8; ++j) ones[j] = (short)0x3F80;

    float4v oacc[4];
#pragma unroll
    for (int i = 0; i < 4; ++i) oacc[i] = (float4v){0.f, 0.f, 0.f, 0.f};
    float4v lsum = (float4v){0.f, 0.f, 0.f, 0.f};
    float mx = -1e30f;
    uint4v vrg;
    float4v sA[4], sB[4];

    auto stageK = [&](int st, int buf) {
        const unsigned short* ga =
            kb + (size_t)(st * 64 + (w >> 1) * 16 + l16) * DH + (w & 1) * 32 + g * 8;
        gld16(ga, &Kb[buf][w * 512]);
    };
    auto loadV = [&](int st) {
        const unsigned short* ga =
            vb + (size_t)((w >> 1) * 16 + l16) * NTOK + st * 64 + (w & 1) * 32 + g * 4;
        uint2v lo = *(const uint2v*)ga;
        uint2v hi = *(const uint2v*)(ga + 16);
        vrg = (uint4v){lo[0], lo[1], hi[0], hi[1]};
    };
    auto writeV = [&](int buf) {
        *(uint4v*)&Vb[buf][w * 512 + l * 8] = vrg;
    };
    auto qkcomp = [&](int buf, float4v (&s)[4]) {
#pragma unroll
        for (int jk = 0; jk < 4; ++jk) s[jk] = (float4v){0.f, 0.f, 0.f, 0.f};
        __builtin_amdgcn_s_setprio(1);
#pragma unroll
        for (int jk = 0; jk < 4; ++jk) {
            short8v kf0 = *(const short8v*)&Kb[buf][(jk * 2 + 0) * 512 + l * 8];
            short8v kf1 = *(const short8v*)&Kb[buf][(jk * 2 + 1) * 512 + l * 8];
            s[jk] = mfma32(kf0, qf[0], s[jk]);
            s[jk] = mfma32(kf1, qf[1], s[jk]);
        }
        __builtin_amdgcn_s_setprio(0);
    };

    auto body = [&](int i, float4v (&scur)[4], float4v (&snext)[4]) {
        const bool pre1 = (i + 1 < cnt), pre2 = (i + 2 < cnt);
        if (pre2) stageK(tlist[i + 2], (i + 2) % 3);
        if (pre1) loadV(tlist[i + 1]);
        // ---- max-reduce + defer-max rescale on scur ----
        float tm = -1e30f;
#pragma unroll
        for (int jk = 0; jk < 4; ++jk) {
            float4v s4 = scur[jk];
            tm = fmaxf(tm, fmaxf(fmaxf(s4[0], s4[1]), fmaxf(s4[2], s4[3])));
        }
        tm = fmaxf(tm, __shfl_xor(tm, 16));
        tm = fmaxf(tm, __shfl_xor(tm, 32));
        if (!__all(tm <= mx + 8.0f)) {
            float mnew = fmaxf(mx, tm);
            float alpha = exp2f(mx - mnew);
#pragma unroll
            for (int r = 0; r < 4; ++r) lsum[r] *= alpha;
#pragma unroll
            for (int md = 0; md < 4; ++md)
#pragma unroll
                for (int r = 0; r < 4; ++r) oacc[md][r] *= alpha;
            mx = mnew;
        }
        // ---- QK(i+1) into the other sacc bank (overlaps exps below) ----
        if (pre1) qkcomp((i + 1) % 3, snext);
        // ---- exps + pack (VALU/trans pipe) ----
        short8v pf[2];
#pragma unroll
        for (int cc = 0; cc < 2; ++cc) {
            short8v pv;
#pragma unroll
            for (int r = 0; r < 4; ++r) {
                pv[r] = (short)b2s(exp2f(scur[2 * cc][r] - mx));
                pv[r + 4] = (short)b2s(exp2f(scur[2 * cc + 1][r] - mx));
            }
            pf[cc] = pv;
        }
        // ---- PV(i) + MFMA row-sum from Vb[i&1] ----
        __builtin_amdgcn_s_setprio(1);
#pragma unroll
        for (int cc = 0; cc < 2; ++cc) lsum = mfma32(ones, pf[cc], lsum);
#pragma unroll
        for (int md = 0; md < 4; ++md)
#pragma unroll
            for (int cc = 0; cc < 2; ++cc) {
                short8v vf = *(const short8v*)&Vb[i & 1][(md * 2 + cc) * 512 + l * 8];
                oacc[md] = mfma32(vf, pf[cc], oacc[md]);
            }
        __builtin_amdgcn_s_setprio(0);
        if (pre1) writeV((i + 1) & 1);
        __syncthreads();  // drains K staging; V(i+1) visible; all reads of this iter done
    };

    if (cnt > 0) {
        stageK(tlist[0], 0);
        loadV(tlist[0]);
        if (cnt > 1) stageK(tlist[1], 1);
        writeV(0);
        __syncthreads();   // K(0),K(1) staged + V(0) visible
        qkcomp(0, sA);     // QK(0)
        for (int i = 0; i < cnt; i += 2) {
            body(i, sA, sB);
            if (i + 1 < cnt) body(i + 1, sB, sA);
        }
    }
    float lrow = lsum[0];
    float inv = lrow > 0.f ? 1.0f / lrow : 0.f;
    int q = q0 + l16;
#pragma unroll
    for (int md = 0; md < 4; ++md) {
        short4v o;
#pragma unroll
        for (int r = 0; r < 4; ++r) o[r] = (short)b2s(oacc[md][r] * inv);
        *(short4v*)(otmp + (size_t)(b * NTOK + q) * NINNER + h * DH + md * 16 + g * 4) = o;
    }
}

extern "C" void kernel_launch(void* const* d_in, const int* in_sizes, int n_in,
                              void* d_out, int out_size, void* d_ws, size_t ws_size,
                              hipStream_t stream) {
    (void)in_sizes; (void)n_in; (void)out_size; (void)ws_size;
    const float* x = (const float*)d_in[0];
    const float* y = (const float*)d_in[1];
    const int* tmask = (const int*)d_in[2];
    const float* Wq = (const float*)d_in[3];
    const float* Wk = (const float*)d_in[4];
    const float* Wv = (const float*)d_in[5];
    const float* Wo = (const float*)d_in[6];
    const float* bo = (const float*)d_in[7];
    const float* pe = (const float*)d_in[8];
    const float* gw = (const float*)d_in[9];
    const float* gb = (const float*)d_in[10];

    char* ws = (char*)d_ws;
    const size_t MB = 1u << 20;
    unsigned short* xpb  = (unsigned short*)(ws + 0);         // 4MB
    unsigned short* ypb  = (unsigned short*)(ws + 4 * MB);    // 4MB
    unsigned short* wall = (unsigned short*)(ws + 8 * MB);    // 3MB [3072][512]
    unsigned short* wot  = (unsigned short*)(ws + 11 * MB);   // 1MB [512][1024]
    unsigned short* qh   = (unsigned short*)(ws + 12 * MB);   // 8MB  [B,H,n,64] bf16
    unsigned short* kh   = (unsigned short*)(ws + 20 * MB);   // 8MB
    unsigned short* vt   = (unsigned short*)(ws + 28 * MB);   // 8MB  [B,H,64,n] bf16
    unsigned short* otm  = (unsigned short*)(ws + 36 * MB);   // 8MB  [B*n,1024] bf16
    float* ct = (float*)(ws + 44 * MB);                       // 256KB
    float* st = (float*)(ws + 44 * MB + 256 * 1024);          // 256KB
    unsigned short* gv = (unsigned short*)(ws + 45 * MB);     // 2KB
    float* bg = (float*)(ws + 45 * MB + 4096);                // 4B
    float* outp = (float*)d_out;

    k_pre<<<2833, 256, 0, stream>>>(x, y, pe, xpb, ypb, Wq, Wk, Wv, Wo, gw, gb, bo,
                                    wall, wot, ct, st, gv, bg);
    // merged QKV: q,k from x (bug-compatible with reference); v from y.
    k_qkv<<<dim3(24, 32), 256, 0, stream>>>(xpb, ypb, wall, qh, kh, vt, ct, st,
                                            0.125f * LOG2E);
    k_attn<<<512, 512, 0, stream>>>(qh, kh, vt, tmask, otm);
    k_oproj<<<dim3(8, 64), 256, 0, stream>>>(otm, wot, bo, gv, bg, outp);
}

// Round 21
// 111.219 us; speedup vs baseline: 2.3488x; 1.0392x over previous
//
#include <hip/hip_runtime.h>
#include <hip/hip_bf16.h>

typedef __attribute__((ext_vector_type(4))) short short4v;
typedef __attribute__((ext_vector_type(8))) short short8v;
typedef __attribute__((ext_vector_type(4))) float float4v;
typedef __attribute__((ext_vector_type(2))) unsigned int uint2v;
typedef __attribute__((ext_vector_type(4))) unsigned int uint4v;

#define NTOK 2048      // n = T*S
#define MROWS 4096     // B*n
#define DMODEL 512
#define NINNER 1024
#define DH 64
#define HH 16
#define LOG2E 1.4426950408889634f

__device__ __forceinline__ unsigned short b2s(float f) {
    __hip_bfloat16 h = __float2bfloat16(f);
    return __builtin_bit_cast(unsigned short, h);
}
__device__ __forceinline__ float bf2f(unsigned short h) {
    unsigned int u = ((unsigned int)h) << 16;
    return __builtin_bit_cast(float, u);
}

__device__ __forceinline__ float4v mfma32(short8v a, short8v b, float4v c) {
    return __builtin_amdgcn_mfma_f32_16x16x32_bf16(a, b, c, 0, 0, 0);
}

__device__ __forceinline__ void gld16(const void* g, void* l) {
    __builtin_amdgcn_global_load_lds((const __attribute__((address_space(1))) void*)g,
                                     (__attribute__((address_space(3))) void*)l, 16, 0, 0);
}

// ---- fused prologue (+ scratch-free attn block schedule) ----
__global__ void k_pre(const float* __restrict__ x, const float* __restrict__ y,
                      const float* __restrict__ pe,
                      unsigned short* __restrict__ xpb, unsigned short* __restrict__ ypb,
                      const float* __restrict__ Wq, const float* __restrict__ Wk,
                      const float* __restrict__ Wv, const float* __restrict__ Wo,
                      const float* __restrict__ gwv, const float* __restrict__ gbv,
                      const float* __restrict__ bo, const int* __restrict__ tmask,
                      unsigned short* __restrict__ wall, unsigned short* __restrict__ wot,
                      float* __restrict__ ctab, float* __restrict__ stab,
                      unsigned short* __restrict__ gvp, float* __restrict__ bgp,
                      int* __restrict__ schd) {
    __shared__ float tl[64][65];
    __shared__ int scnt[64];
    const int blk = blockIdx.x;
    const int tid = threadIdx.x;
    if (blk < 2048) {  // x,y + pos_emb
        int e0 = (blk * 256 + tid) * 4;
        int row = e0 >> 9, col = e0 & 511;
        int t = (row & (NTOK - 1)) >> 7;
        const float4v xv = *(const float4v*)(x + e0);
        const float4v yv = *(const float4v*)(y + e0);
        const float4v pv = *(const float4v*)(pe + t * DMODEL + col);
        short4v xo, yo;
#pragma unroll
        for (int i = 0; i < 4; ++i) {
            xo[i] = (short)b2s(xv[i] + pv[i]);
            yo[i] = (short)b2s(yv[i] + pv[i]);
        }
        *(short4v*)(xpb + e0) = xo;
        *(short4v*)(ypb + e0) = yo;
    } else if (blk < 2560) {  // weight transpose tiles
        int t = blk - 2048;
        const float* W;
        unsigned short* dst;
        int K, N, k0, n0;
        if (t < 384) {
            int which = t / 128, tile = t % 128;
            W = (which == 0) ? Wq : (which == 1) ? Wk : Wv;
            dst = wall + (size_t)which * 1024 * 512;
            K = 512; N = 1024;
            k0 = (tile >> 4) * 64; n0 = (tile & 15) * 64;
        } else {
            int tile = t - 384;
            W = Wo; dst = wot;
            K = 1024; N = 512;
            k0 = (tile >> 3) * 64; n0 = (tile & 7) * 64;
        }
        int tx = tid & 63, ty4 = tid >> 6;
#pragma unroll
        for (int p = 0; p < 16; ++p) {
            int ky = p * 4 + ty4;
            tl[ky][tx] = W[(size_t)(k0 + ky) * N + n0 + tx];
        }
        __syncthreads();
#pragma unroll
        for (int p = 0; p < 16; ++p) {
            int ny = p * 4 + ty4;
            dst[(size_t)(n0 + ny) * K + k0 + tx] = b2s(tl[tx][ny]);
        }
    } else if (blk < 2816) {  // rope tables [2048][32]
        int idx = (blk - 2560) * 256 + tid;
        int p = idx >> 5, j = idx & 31;
        float invf = powf(10000.0f, -(float)(2 * j) * (1.0f / 64.0f));
        float f = (float)p * invf;
        ctab[idx] = cosf(f);
        stab[idx] = sinf(f);
    } else if (blk < 2832) {  // gv = Wo @ gate_w
        int base = (blk - 2816) * 64;
        int w = tid >> 6, l = tid & 63, l16 = l & 15, g = l >> 4;
        int row = base + w * 16 + l16;
        const float* wr = Wo + (size_t)row * 512 + g * 128;
        const float* gr = gwv + g * 128;
        float s = 0.f;
#pragma unroll
        for (int t = 0; t < 32; ++t) {
            float4v a = *(const float4v*)(wr + t * 4);
            float4v b = *(const float4v*)(gr + t * 4);
            s += a[0] * b[0] + a[1] * b[1] + a[2] * b[2] + a[3] * b[3];
        }
        s += __shfl_xor(s, 16);
        s += __shfl_xor(s, 32);
        if (g == 0) gvp[row] = b2s(s);
    } else if (blk == 2832) {  // bg
        if (tid < 64) {
            float s = 0.f;
#pragma unroll
            for (int t = 0; t < 8; ++t) s += bo[tid + t * 64] * gwv[tid + t * 64];
#pragma unroll
            for (int off = 32; off > 0; off >>= 1) s += __shfl_xor(s, off);
            if (tid == 0) bgp[0] = s + gbv[0];
        }
    } else {  // blk in [2833,2841): attn schedule for XCD group kx (SCRATCH-FREE)
        // rank-by-counting: no register arrays, no dynamic register indexing.
        // Unit with rank r -> block slot p = r<32 ? r : 95-r, so co-resident
        // slots (p, p+32) pair rank r with rank 63-r (complementary cost).
        // Grouping by blk&7 == kx preserves the XCD/L2 locality.
        int kx = blk - 2833;
        if (tid < 64) {
            int uu = kx * 64 + tid;
            int tti = uu & 15, bb = uu >> 8;
            int m = 0;
#pragma unroll
            for (int jj = 0; jj < 16; ++jj)
                m += (tmask[(bb * 16 + tti) * 16 + jj] != 0);
            scnt[tid] = m;
        }
        __syncthreads();
        if (tid < 64) {
            int my = scnt[tid];
            int rank = 0;
            for (int j = 0; j < 64; ++j) {
                int c = scnt[j];
                rank += (c > my || (c == my && j < tid)) ? 1 : 0;
            }
            int p = (rank < 32) ? rank : (95 - rank);
            schd[8 * p + kx] = kx * 64 + tid;
        }
    }
}

// ---- QKV GEMM: 128x128 tile, BK=32, 4 waves (2x2), 4x4 frags/wave ----
__global__ __launch_bounds__(256) void k_qkv(const unsigned short* __restrict__ A,
                                             const unsigned short* __restrict__ A2,
                                             const unsigned short* __restrict__ Bt,
                                             unsigned short* __restrict__ Cq,
                                             unsigned short* __restrict__ Ck,
                                             unsigned short* __restrict__ Cvv,
                                             const float* __restrict__ ctab,
                                             const float* __restrict__ stab,
                                             float scale) {
    __shared__ unsigned short Ab[2][4096];
    __shared__ unsigned short Bb[2][4096];
    const int tid = threadIdx.x;
    const int w = tid >> 6, l = tid & 63, l16 = l & 15, g = l >> 4;
    const int wm = w >> 1, wn = w & 1;
    const int m0 = blockIdx.y * 128, n0 = blockIdx.x * 128;
    const unsigned short* Ap = (n0 >= 2048) ? A2 : A;
    float4v acc[4][4];
#pragma unroll
    for (int i = 0; i < 4; ++i)
#pragma unroll
        for (int j = 0; j < 4; ++j) acc[i][j] = (float4v){0.f, 0.f, 0.f, 0.f};

    auto stage = [&](int t, int buf) {
        int k0 = t * 32;
#pragma unroll
        for (int it = 0; it < 2; ++it) {
            int f = it * 4 + w;
            gld16(Ap + (size_t)(m0 + f * 16 + l16) * 512 + k0 + g * 8, &Ab[buf][f * 512]);
            gld16(Bt + (size_t)(n0 + f * 16 + l16) * 512 + k0 + g * 8, &Bb[buf][f * 512]);
        }
    };

    stage(0, 0);
    __syncthreads();
    for (int t = 0; t < 16; ++t) {
        const int cur = t & 1;
        if (t + 1 < 16) stage(t + 1, cur ^ 1);
        short8v af[4], bf[4];
#pragma unroll
        for (int mi = 0; mi < 4; ++mi)
            af[mi] = *(const short8v*)&Ab[cur][(wm * 4 + mi) * 512 + l * 8];
#pragma unroll
        for (int nj = 0; nj < 4; ++nj)
            bf[nj] = *(const short8v*)&Bb[cur][(wn * 4 + nj) * 512 + l * 8];
        __builtin_amdgcn_s_setprio(1);
#pragma unroll
        for (int mi = 0; mi < 4; ++mi)
#pragma unroll
            for (int nj = 0; nj < 4; ++nj)
                acc[mi][nj] = mfma32(af[mi], bf[nj], acc[mi][nj]);
        __builtin_amdgcn_s_setprio(0);
        __syncthreads();
    }

    const int hh = (n0 + wn * 64) >> 6;
    const int head = hh & 15;
    if (hh < 32) {
        unsigned short* out = (hh < 16) ? Cq : Ck;
        const float sc = (hh < 16) ? scale : 1.0f;
#pragma unroll
        for (int mi = 0; mi < 4; ++mi)
#pragma unroll
            for (int r = 0; r < 4; ++r) {
                int row = m0 + wm * 64 + mi * 16 + g * 4 + r;
                int b = row >> 11, pos = row & (NTOK - 1);
                const float* cr = ctab + pos * 32;
                const float* sr = stab + pos * 32;
                unsigned short* ob = out + (size_t)((b * HH + head) * NTOK + pos) * DH;
#pragma unroll
                for (int nj = 0; nj < 2; ++nj) {
                    int j = nj * 16 + l16;
                    float c = cr[j], s = sr[j];
                    float v1 = acc[mi][nj][r], v2 = acc[mi][nj + 2][r];
                    ob[j] = b2s((v1 * c - v2 * s) * sc);
                    ob[j + 32] = b2s((v2 * c + v1 * s) * sc);
                }
            }
    } else {
#pragma unroll
        for (int mi = 0; mi < 4; ++mi)
#pragma unroll
            for (int nj = 0; nj < 4; ++nj) {
                int d = nj * 16 + l16;
                int row0 = m0 + wm * 64 + mi * 16 + g * 4;
                int b = row0 >> 11, pos0 = row0 & (NTOK - 1);
                short4v o;
#pragma unroll
                for (int r = 0; r < 4; ++r) o[r] = (short)b2s(acc[mi][nj][r]);
                *(short4v*)(Cvv + (size_t)((b * HH + head) * DH + d) * NTOK + pos0) = o;
            }
    }
}

// ---- O-projection v3: 64x64 tile, grid (8,64); gate-dot fused via broadcast-B MFMA ----
__global__ __launch_bounds__(256) void k_oproj(const unsigned short* __restrict__ A,
                                               const unsigned short* __restrict__ Bt,
                                               const float* __restrict__ bo,
                                               const unsigned short* __restrict__ gv,
                                               const float* __restrict__ bgp,
                                               float* __restrict__ out) {
    __shared__ unsigned short Ab[2][2048];  // 4 frags x 512 shorts (64 rows x 32 k)
    __shared__ unsigned short Bb[2][2048];
    const int tid = threadIdx.x;
    const int w = tid >> 6, l = tid & 63, l16 = l & 15, g = l >> 4;
    const int m0 = blockIdx.y * 64, n0 = blockIdx.x * 64;
    float4v acc[4];
#pragma unroll
    for (int j = 0; j < 4; ++j) acc[j] = (float4v){0.f, 0.f, 0.f, 0.f};
    float4v gacc = (float4v){0.f, 0.f, 0.f, 0.f};

    auto stage = [&](int t, int buf) {
        int k0 = t * 32;
        gld16(A + (size_t)(m0 + w * 16 + l16) * 1024 + k0 + g * 8, &Ab[buf][w * 512]);
        gld16(Bt + (size_t)(n0 + w * 16 + l16) * 1024 + k0 + g * 8, &Bb[buf][w * 512]);
    };

    stage(0, 0);
    __syncthreads();
    for (int t = 0; t < 32; ++t) {
        const int cur = t & 1;
        if (t + 1 < 32) stage(t + 1, cur ^ 1);
        short8v af = *(const short8v*)&Ab[cur][w * 512 + l * 8];
        short8v bf[4];
#pragma unroll
        for (int nj = 0; nj < 4; ++nj)
            bf[nj] = *(const short8v*)&Bb[cur][nj * 512 + l * 8];
        short8v gvf = *(const short8v*)(gv + t * 32 + g * 8);  // broadcast B-frag
        __builtin_amdgcn_s_setprio(1);
#pragma unroll
        for (int nj = 0; nj < 4; ++nj)
            acc[nj] = mfma32(af, bf[nj], acc[nj]);
        gacc = mfma32(af, gvf, gacc);
        __builtin_amdgcn_s_setprio(0);
        __syncthreads();
    }
    const float bg = bgp[0];
    float gl[4];
#pragma unroll
    for (int r = 0; r < 4; ++r) gl[r] = 1.0f / (1.0f + __expf(-(gacc[r] + bg)));
#pragma unroll
    for (int nj = 0; nj < 4; ++nj) {
        int col = n0 + nj * 16 + l16;
        float bv = bo[col];
#pragma unroll
        for (int r = 0; r < 4; ++r) {
            int row = m0 + w * 16 + g * 4 + r;
            out[(size_t)row * 512 + col] = (acc[nj][r] + bv) * gl[r];
        }
    }
}

// ---- masked flash attention v10 + scheduled block->unit map (load balance) ----
// 8 waves/512 thr, wave owns 16 q-rows, KVBLK=64, grid 512. u = schd[blk]:
// complementary-cost pairing within each XCD group (L2 locality preserved).
// K TRIPLE-buffered (staged distance-2 via gld16); V double-buffered (reg->LDS).
__global__ __launch_bounds__(512) void k_attn(const unsigned short* __restrict__ qh,
                                              const unsigned short* __restrict__ kh,
                                              const unsigned short* __restrict__ vt,
                                              const int* __restrict__ tmask,
                                              const int* __restrict__ schd,
                                              unsigned short* __restrict__ otmp) {
    __shared__ unsigned short Kb[3][4096];  // 8 frags x 512 shorts (64 kv x 64 d)
    __shared__ unsigned short Vb[2][4096];
    __shared__ int tlist[33];
    const int blk = blockIdx.x;
    const int u = schd[blk];
    const int ti = u & 15, h = (u >> 4) & 15, b = u >> 8;
    const int tid = threadIdx.x, w = tid >> 6, l = tid & 63, l16 = l & 15, g = l >> 4;
    if (tid == 0) {
        int c = 0;
        for (int j = 0; j < 16; ++j)
            if (tmask[(b * 16 + ti) * 16 + j]) { tlist[c++] = 2 * j; tlist[c++] = 2 * j + 1; }
        tlist[32] = c;
    }
    __syncthreads();
    const int cnt = tlist[32];
    const unsigned short* qb = qh + (size_t)((b * HH + h) * NTOK) * DH;
    const unsigned short* kb = kh + (size_t)((b * HH + h) * NTOK) * DH;
    const unsigned short* vb = vt + (size_t)((b * HH + h) * DH) * NTOK;
    const int q0 = ti * 128 + w * 16;

    short8v qf[2];
#pragma unroll
    for (int c = 0; c < 2; ++c)
        qf[c] = *(const short8v*)(qb + (size_t)(q0 + l16) * DH + c * 32 + g * 8);

    short8v ones;  // all-ones bf16 A-frag for the MFMA row-sum
#pragma unroll
    for (int j = 0; j < 8; ++j) ones[j] = (short)0x3F80;

    float4v oacc[4];
#pragma unroll
    for (int i = 0; i < 4; ++i) oacc[i] = (float4v){0.f, 0.f, 0.f, 0.f};
    float4v lsum = (float4v){0.f, 0.f, 0.f, 0.f};
    float mx = -1e30f;
    uint4v vrg;
    float4v sA[4], sB[4];

    auto stageK = [&](int st, int buf) {
        const unsigned short* ga =
            kb + (size_t)(st * 64 + (w >> 1) * 16 + l16) * DH + (w & 1) * 32 + g * 8;
        gld16(ga, &Kb[buf][w * 512]);
    };
    auto loadV = [&](int st) {
        const unsigned short* ga =
            vb + (size_t)((w >> 1) * 16 + l16) * NTOK + st * 64 + (w & 1) * 32 + g * 4;
        uint2v lo = *(const uint2v*)ga;
        uint2v hi = *(const uint2v*)(ga + 16);
        vrg = (uint4v){lo[0], lo[1], hi[0], hi[1]};
    };
    auto writeV = [&](int buf) {
        *(uint4v*)&Vb[buf][w * 512 + l * 8] = vrg;
    };
    auto qkcomp = [&](int buf, float4v (&s)[4]) {
#pragma unroll
        for (int jk = 0; jk < 4; ++jk) s[jk] = (float4v){0.f, 0.f, 0.f, 0.f};
        __builtin_amdgcn_s_setprio(1);
#pragma unroll
        for (int jk = 0; jk < 4; ++jk) {
            short8v kf0 = *(const short8v*)&Kb[buf][(jk * 2 + 0) * 512 + l * 8];
            short8v kf1 = *(const short8v*)&Kb[buf][(jk * 2 + 1) * 512 + l * 8];
            s[jk] = mfma32(kf0, qf[0], s[jk]);
            s[jk] = mfma32(kf1, qf[1], s[jk]);
        }
        __builtin_amdgcn_s_setprio(0);
    };

    auto body = [&](int i, float4v (&scur)[4], float4v (&snext)[4]) {
        const bool pre1 = (i + 1 < cnt), pre2 = (i + 2 < cnt);
        if (pre2) stageK(tlist[i + 2], (i + 2) % 3);
        if (pre1) loadV(tlist[i + 1]);
        // ---- max-reduce + defer-max rescale on scur ----
        float tm = -1e30f;
#pragma unroll
        for (int jk = 0; jk < 4; ++jk) {
            float4v s4 = scur[jk];
            tm = fmaxf(tm, fmaxf(fmaxf(s4[0], s4[1]), fmaxf(s4[2], s4[3])));
        }
        tm = fmaxf(tm, __shfl_xor(tm, 16));
        tm = fmaxf(tm, __shfl_xor(tm, 32));
        if (!__all(tm <= mx + 8.0f)) {
            float mnew = fmaxf(mx, tm);
            float alpha = exp2f(mx - mnew);
#pragma unroll
            for (int r = 0; r < 4; ++r) lsum[r] *= alpha;
#pragma unroll
            for (int md = 0; md < 4; ++md)
#pragma unroll
                for (int r = 0; r < 4; ++r) oacc[md][r] *= alpha;
            mx = mnew;
        }
        // ---- QK(i+1) into the other sacc bank (overlaps exps below) ----
        if (pre1) qkcomp((i + 1) % 3, snext);
        // ---- exps + pack (VALU/trans pipe) ----
        short8v pf[2];
#pragma unroll
        for (int cc = 0; cc < 2; ++cc) {
            short8v pv;
#pragma unroll
            for (int r = 0; r < 4; ++r) {
                pv[r] = (short)b2s(exp2f(scur[2 * cc][r] - mx));
                pv[r + 4] = (short)b2s(exp2f(scur[2 * cc + 1][r] - mx));
            }
            pf[cc] = pv;
        }
        // ---- PV(i) + MFMA row-sum from Vb[i&1] ----
        __builtin_amdgcn_s_setprio(1);
#pragma unroll
        for (int cc = 0; cc < 2; ++cc) lsum = mfma32(ones, pf[cc], lsum);
#pragma unroll
        for (int md = 0; md < 4; ++md)
#pragma unroll
            for (int cc = 0; cc < 2; ++cc) {
                short8v vf = *(const short8v*)&Vb[i & 1][(md * 2 + cc) * 512 + l * 8];
                oacc[md] = mfma32(vf, pf[cc], oacc[md]);
            }
        __builtin_amdgcn_s_setprio(0);
        if (pre1) writeV((i + 1) & 1);
        __syncthreads();  // drains K staging; V(i+1) visible; all reads of this iter done
    };

    if (cnt > 0) {
        stageK(tlist[0], 0);
        loadV(tlist[0]);
        if (cnt > 1) stageK(tlist[1], 1);
        writeV(0);
        __syncthreads();   // K(0),K(1) staged + V(0) visible
        qkcomp(0, sA);     // QK(0)
        for (int i = 0; i < cnt; i += 2) {
            body(i, sA, sB);
            if (i + 1 < cnt) body(i + 1, sB, sA);
        }
    }
    float lrow = lsum[0];
    float inv = lrow > 0.f ? 1.0f / lrow : 0.f;
    int q = q0 + l16;
#pragma unroll
    for (int md = 0; md < 4; ++md) {
        short4v o;
#pragma unroll
        for (int r = 0; r < 4; ++r) o[r] = (short)b2s(oacc[md][r] * inv);
        *(short4v*)(otmp + (size_t)(b * NTOK + q) * NINNER + h * DH + md * 16 + g * 4) = o;
    }
}

extern "C" void kernel_launch(void* const* d_in, const int* in_sizes, int n_in,
                              void* d_out, int out_size, void* d_ws, size_t ws_size,
                              hipStream_t stream) {
    (void)in_sizes; (void)n_in; (void)out_size; (void)ws_size;
    const float* x = (const float*)d_in[0];
    const float* y = (const float*)d_in[1];
    const int* tmask = (const int*)d_in[2];
    const float* Wq = (const float*)d_in[3];
    const float* Wk = (const float*)d_in[4];
    const float* Wv = (const float*)d_in[5];
    const float* Wo = (const float*)d_in[6];
    const float* bo = (const float*)d_in[7];
    const float* pe = (const float*)d_in[8];
    const float* gw = (const float*)d_in[9];
    const float* gb = (const float*)d_in[10];

    char* ws = (char*)d_ws;
    const size_t MB = 1u << 20;
    unsigned short* xpb  = (unsigned short*)(ws + 0);         // 4MB
    unsigned short* ypb  = (unsigned short*)(ws + 4 * MB);    // 4MB
    unsigned short* wall = (unsigned short*)(ws + 8 * MB);    // 3MB [3072][512]
    unsigned short* wot  = (unsigned short*)(ws + 11 * MB);   // 1MB [512][1024]
    unsigned short* qh   = (unsigned short*)(ws + 12 * MB);   // 8MB  [B,H,n,64] bf16
    unsigned short* kh   = (unsigned short*)(ws + 20 * MB);   // 8MB
    unsigned short* vt   = (unsigned short*)(ws + 28 * MB);   // 8MB  [B,H,64,n] bf16
    unsigned short* otm  = (unsigned short*)(ws + 36 * MB);   // 8MB  [B*n,1024] bf16
    float* ct = (float*)(ws + 44 * MB);                       // 256KB
    float* st = (float*)(ws + 44 * MB + 256 * 1024);          // 256KB
    unsigned short* gv = (unsigned short*)(ws + 45 * MB);     // 2KB
    float* bg = (float*)(ws + 45 * MB + 4096);                // 4B
    int* schd = (int*)(ws + 45 * MB + 8192);                  // 2KB
    float* outp = (float*)d_out;

    k_pre<<<2841, 256, 0, stream>>>(x, y, pe, xpb, ypb, Wq, Wk, Wv, Wo, gw, gb, bo,
                                    tmask, wall, wot, ct, st, gv, bg, schd);
    // merged QKV: q,k from x (bug-compatible with reference); v from y.
    k_qkv<<<dim3(24, 32), 256, 0, stream>>>(xpb, ypb, wall, qh, kh, vt, ct, st,
                                            0.125f * LOG2E);
    k_attn<<<512, 512, 0, stream>>>(qh, kh, vt, tmask, schd, otm);
    k_oproj<<<dim3(8, 64), 256, 0, stream>>>(otm, wot, bo, gv, bg, outp);
}